// Round 13
// baseline (129.247 us; speedup 1.0000x reference)
//
#include <hip/hip_runtime.h>

// TopNGating: B=2, N=4096, DIM=2048, 8 experts, top-2, cap=640
// Outputs (concat): dispatch[2,4096,8,640], combine[2,4096,8,640], balance_loss, router_z_loss
//
// Structure (R13): 2 kernels.
//  kfat: 4096 blocks x 640 threads (10 waves): waves 0-7 nt-stream zeros
//        (335.5MB total), waves 8-9 gate one token each (LDS-free, W from L2,
//        nt-loads for the streaming x). Uniform 8:2 store:gate wave mix on
//        every CU -> stores stay saturated, no gate-only CU tails.
//  kscan: 16 (b,e) blocks: prefix scan + direct scatter + loss atomicAdds.

#define DIMX 2048
#define NG   8
#define NB   2
#define NSEQ 4096
#define NTOK (NB*NSEQ)
#define CAPE 640
#define ROW  (NG*CAPE)                 // 5120 floats per token per tensor
#define DCNT ((size_t)NTOK*ROW)        // 41943040 floats per dense output

typedef float vfloat4 __attribute__((ext_vector_type(4)));   // native vec for nontemporal builtins

struct Ws {
  int   pk[NTOK];                 // e0 | e1<<4 | routed1<<8
  float g0[NTOK];                 // renormalized top-1 gate
  float g1[NTOK];                 // renormalized top-2 gate
  float z2[NTOK];                 // lse^2 per token
  float raws[(size_t)NTOK*NG];    // raw softmax gates [token][e]
};

// ---------------- fused: zero-fill (waves 0-7) + gate (waves 8-9) ----------------
__global__ __launch_bounds__(640) void kfat(const float* __restrict__ x,
                                            const float* __restrict__ W,
                                            const float* __restrict__ probs,
                                            Ws* __restrict__ ws,
                                            float* __restrict__ out) {
  int bid = blockIdx.x;                         // 0..4095
  int tid = threadIdx.x;
  int wave = tid >> 6, lane = tid & 63;

  if (wave < 8) {
    // ---- zero波: this block covers 5120 float4s; wave w stores rows w*10..w*10+9 ----
    vfloat4* o4 = (vfloat4*)out;
    long base = (long)bid * 5120 + wave * 640 + lane;
    vfloat4 z = {0.f, 0.f, 0.f, 0.f};
#pragma unroll
    for (int k = 0; k < 10; ++k) __builtin_nontemporal_store(z, o4 + base + k * 64);
    if (bid == 0 && tid == 0) { out[2 * DCNT] = 0.f; out[2 * DCNT + 1] = 0.f; }  // loss accum init
    return;
  }

  // ---- gate wave: token = bid*2 + (wave-8); LDS-free, W from L2, x nt-load ----
  int token = bid * 2 + (wave - 8);

  const vfloat4* xp = (const vfloat4*)(x + (size_t)token * DIMX);
  const float4*  W4 = (const float4*)W;

  float acc[NG] = {0.f,0.f,0.f,0.f,0.f,0.f,0.f,0.f};
#pragma unroll
  for (int j = 0; j < 8; ++j) {
    vfloat4 xj = __builtin_nontemporal_load(xp + j * 64 + lane);   // 1KB coalesced, stream (no L2 pollute)
#pragma unroll
    for (int e = 0; e < NG; ++e) {
      float4 w = W4[e * 512 + j * 64 + lane];   // 1KB coalesced, L2-hit
      acc[e] = fmaf(xj.x, w.x, acc[e]);
      acc[e] = fmaf(xj.y, w.y, acc[e]);
      acc[e] = fmaf(xj.z, w.z, acc[e]);
      acc[e] = fmaf(xj.w, w.w, acc[e]);
    }
  }
#pragma unroll
  for (int e = 0; e < NG; ++e) {
#pragma unroll
    for (int off = 32; off > 0; off >>= 1) acc[e] += __shfl_xor(acc[e], off, 64);
  }

  // softmax over 8 gates (wave-uniform, redundant on all lanes)
  float m = acc[0];
#pragma unroll
  for (int e = 1; e < NG; ++e) m = fmaxf(m, acc[e]);
  float ex[NG], s = 0.f;
#pragma unroll
  for (int e = 0; e < NG; ++e) { ex[e] = expf(acc[e] - m); s += ex[e]; }
  float raw[NG];
#pragma unroll
  for (int e = 0; e < NG; ++e) raw[e] = ex[e] / s;

  // top-2, ties -> lowest index (strict >)
  int e0i = 0; float g0v = raw[0];
#pragma unroll
  for (int e = 1; e < NG; ++e) if (raw[e] > g0v) { g0v = raw[e]; e0i = e; }
  int e1i = -1; float g1v = -1.f;
#pragma unroll
  for (int e = 0; e < NG; ++e) if (e != e0i && raw[e] > g1v) { g1v = raw[e]; e1i = e; }

  float denom = g0v + g1v;
  if (denom < 1e-9f) denom = 1e-9f;
  float g0n = g0v / denom, g1n = g1v / denom;

  float p1 = probs[NTOK + token];               // probs[1][b][n], b*NSEQ+n == token
  int rte = (p1 < (g1n / 0.2f)) ? 1 : 0;        // threshold_train = 0.2

  float lse = m + logf(s);

  if (lane < NG) ws->raws[(size_t)token * NG + lane] = raw[lane];
  if (lane == 0) {
    ws->pk[token] = e0i | (e1i << 4) | (rte << 8);
    ws->g0[token] = g0n;  ws->g1[token] = g1n;
    ws->z2[token] = lse * lse;
  }
}

// ---------------- per-(b,e) prefix scans + direct scatter + loss accumulation ----------------
__global__ __launch_bounds__(256) void kscan(const Ws* __restrict__ ws, float* __restrict__ out) {
  __shared__ int   wtot[4];
  __shared__ float wsum[4];
  __shared__ float zsum[4];
  int be = blockIdx.x, b = be >> 3, e = be & 7;
  int t = threadIdx.x, wave = t >> 6, lane = t & 63;
  int base = b * NSEQ;

  // each thread owns 16 consecutive tokens; wave covers contiguous 4KB -> coalesced int4
  int pk[16];
  {
    const int4* pp = (const int4*)(ws->pk + base + t * 16);
#pragma unroll
    for (int j = 0; j < 4; ++j) {
      int4 v = pp[j];
      pk[4*j] = v.x; pk[4*j+1] = v.y; pk[4*j+2] = v.z; pk[4*j+3] = v.w;
    }
  }

  // density_1_proxy partial: sum raw gates for this (b,e)
  float ps = 0.f;
#pragma unroll
  for (int i = 0; i < 16; ++i) ps += ws->raws[(size_t)(base + t * 16 + i) * NG + e];
#pragma unroll
  for (int off = 32; off > 0; off >>= 1) ps += __shfl_xor(ps, off, 64);
  if (lane == 0) wsum[wave] = ps;

  // z-loss slice: this block reduces z2[be*512 .. be*512+512) = 128 float4s
  float zs = 0.f;
  if (t < 128) {
    float4 v = ((const float4*)ws->z2)[be * 128 + t];
    zs = v.x + v.y + v.z + v.w;
  }
#pragma unroll
  for (int off = 32; off > 0; off >>= 1) zs += __shfl_xor(zs, off, 64);
  if (lane == 0) zsum[wave] = zs;

  // ---- k = 0 (always routed) ----
  int cnt = 0;
#pragma unroll
  for (int i = 0; i < 16; ++i) cnt += ((pk[i] & 15) == e);
  int incl = cnt;
#pragma unroll
  for (int off = 1; off < 64; off <<= 1) { int v = __shfl_up(incl, off, 64); if (lane >= off) incl += v; }
  if (lane == 63) wtot[wave] = incl;
  __syncthreads();
  int woff = 0, tot = 0;
#pragma unroll
  for (int w = 0; w < 4; ++w) { int v = wtot[w]; tot += v; if (w < wave) woff += v; }
  int c0 = min(tot, CAPE);
  int p = woff + incl - cnt;          // exclusive prefix for this thread's first token
#pragma unroll
  for (int i = 0; i < 16; ++i) {
    int nn = t * 16 + i;
    if ((pk[i] & 15) == e) {
      if (p < CAPE) {
        size_t o = (size_t)(base + nn) * ROW + e * CAPE + p;
        out[o]        = 1.f;                       // dispatch
        out[DCNT + o] = ws->g0[base + nn];         // combine
      }
      ++p;
    }
  }
  __syncthreads();   // wtot reuse

  // ---- k = 1 (offset by capacity-clipped top-1 count) ----
  cnt = 0;
#pragma unroll
  for (int i = 0; i < 16; ++i) cnt += ((((pk[i] >> 4) & 15) == e) && (pk[i] & 0x100));
  incl = cnt;
#pragma unroll
  for (int off = 1; off < 64; off <<= 1) { int v = __shfl_up(incl, off, 64); if (lane >= off) incl += v; }
  if (lane == 63) wtot[wave] = incl;
  __syncthreads();
  woff = 0;
#pragma unroll
  for (int w = 0; w < 4; ++w) { int v = wtot[w]; if (w < wave) woff += v; }
  p = woff + incl - cnt;
#pragma unroll
  for (int i = 0; i < 16; ++i) {
    int nn = t * 16 + i;
    if ((((pk[i] >> 4) & 15) == e) && (pk[i] & 0x100)) {
      int q = p + c0;
      if (q < CAPE) {
        size_t o = (size_t)(base + nn) * ROW + e * CAPE + q;
        out[o]        = 1.f;                       // dispatch
        out[DCNT + o] = ws->g1[base + nn];         // combine
      }
      ++p;
    }
  }

  if (t == 0) {
    float psum = wsum[0] + wsum[1] + wsum[2] + wsum[3];
    float ztot = zsum[0] + zsum[1] + zsum[2] + zsum[3];
    // balance: sum over 16 (b,e) of (proxy/NSEQ)*(c0/NSEQ), /16 * 64
    atomicAdd(out + 2 * DCNT,     psum * (1.f / NSEQ) * ((float)c0 * (1.f / NSEQ)) * 4.f);
    atomicAdd(out + 2 * DCNT + 1, ztot * (1.f / NTOK));
  }
}

extern "C" void kernel_launch(void* const* d_in, const int* in_sizes, int n_in,
                              void* d_out, int out_size, void* d_ws, size_t ws_size,
                              hipStream_t stream) {
  const float* x     = (const float*)d_in[0];
  const float* W     = (const float*)d_in[1];
  const float* probs = (const float*)d_in[2];
  float* out = (float*)d_out;
  Ws* ws = (Ws*)d_ws;

  kfat<<<4096, 640, 0, stream>>>(x, W, probs, ws, out);
  kscan<<<16, 256, 0, stream>>>(ws, out);
}

// Round 14
// 83.233 us; speedup vs baseline: 1.5528x; 1.5528x over previous
//
#include <hip/hip_runtime.h>

// TopNGating: B=2, N=4096, DIM=2048, 8 experts, top-2, cap=640
// Outputs (concat): dispatch[2,4096,8,640], combine[2,4096,8,640], balance_loss, router_z_loss
//
// Structure (R14): 2 kernels.
//  kfat: 5120 blocks. Block-role split with FRONT-LOADED gates:
//        bid<2048: even->zero block (idx=bid/2), odd->gate block (g=bid/2)
//        bid>=2048: zero block (idx=bid-1024)
//        Gates co-resident with stores early; tail = pure nt-stores at fill rate.
//        Gate path LDS-free (W L2-resident), R2-exact math per token.
//  kscan: 16 (b,e) blocks: prefix scan + direct scatter + loss atomicAdds.

#define DIMX 2048
#define NG   8
#define NB   2
#define NSEQ 4096
#define NTOK (NB*NSEQ)
#define CAPE 640
#define ROW  (NG*CAPE)                 // 5120 floats per token per tensor
#define DCNT ((size_t)NTOK*ROW)        // 41943040 floats per dense output

typedef float vfloat4 __attribute__((ext_vector_type(4)));   // native vec for nontemporal builtin

struct Ws {
  int   pk[NTOK];                 // e0 | e1<<4 | routed1<<8
  float g0[NTOK];                 // renormalized top-1 gate
  float g1[NTOK];                 // renormalized top-2 gate
  float z2[NTOK];                 // lse^2 per token
  float raws[(size_t)NTOK*NG];    // raw softmax gates [token][e]
};

// ---------------- fused: zero-fill + gate, gates front-loaded ----------------
__global__ __launch_bounds__(512) void kfat(const float* __restrict__ x,
                                            const float* __restrict__ W,
                                            const float* __restrict__ probs,
                                            Ws* __restrict__ ws,
                                            float* __restrict__ out) {
  int bid = blockIdx.x;
  int tid = threadIdx.x;

  int g;                                        // role decode
  if (bid < 2048) {
    g = bid >> 1;
    if (!(bid & 1)) {                           // even front half: zero block idx=g
      vfloat4* o4 = (vfloat4*)out;
      long base = (long)g * 5120 + tid;
      vfloat4 z = {0.f, 0.f, 0.f, 0.f};
#pragma unroll
      for (int k = 0; k < 10; ++k) __builtin_nontemporal_store(z, o4 + base + k * 512);
      if (g == 0 && tid == 0) { out[2 * DCNT] = 0.f; out[2 * DCNT + 1] = 0.f; }
      return;
    }
    // odd: fall through to gate block g in [0,1024)
  } else {
    // back 3072 blocks: zero block idx = bid-1024 in [1024,4096)
    int idx = bid - 1024;
    vfloat4* o4 = (vfloat4*)out;
    long base = (long)idx * 5120 + tid;
    vfloat4 z = {0.f, 0.f, 0.f, 0.f};
#pragma unroll
    for (int k = 0; k < 10; ++k) __builtin_nontemporal_store(z, o4 + base + k * 512);
    return;
  }

  // ---- gate block g in [0,1024): 1 token per wave; LDS-free, W from L2 ----
  int wave = tid >> 6, lane = tid & 63;
  int token = g * 8 + wave;

  const float4* xp = (const float4*)(x + (size_t)token * DIMX);
  const float4* W4 = (const float4*)W;

  float acc[NG] = {0.f,0.f,0.f,0.f,0.f,0.f,0.f,0.f};
#pragma unroll
  for (int j = 0; j < 8; ++j) {
    float4 xj = xp[j * 64 + lane];              // 1KB coalesced, HBM
#pragma unroll
    for (int e = 0; e < NG; ++e) {
      float4 w = W4[e * 512 + j * 64 + lane];   // 1KB coalesced, L2-hit
      acc[e] = fmaf(xj.x, w.x, acc[e]);
      acc[e] = fmaf(xj.y, w.y, acc[e]);
      acc[e] = fmaf(xj.z, w.z, acc[e]);
      acc[e] = fmaf(xj.w, w.w, acc[e]);
    }
  }
#pragma unroll
  for (int e = 0; e < NG; ++e) {
#pragma unroll
    for (int off = 32; off > 0; off >>= 1) acc[e] += __shfl_xor(acc[e], off, 64);
  }

  // softmax over 8 gates (wave-uniform, redundant on all lanes)
  float m = acc[0];
#pragma unroll
  for (int e = 1; e < NG; ++e) m = fmaxf(m, acc[e]);
  float ex[NG], s = 0.f;
#pragma unroll
  for (int e = 0; e < NG; ++e) { ex[e] = expf(acc[e] - m); s += ex[e]; }
  float raw[NG];
#pragma unroll
  for (int e = 0; e < NG; ++e) raw[e] = ex[e] / s;

  // top-2, ties -> lowest index (strict >)
  int e0i = 0; float g0v = raw[0];
#pragma unroll
  for (int e = 1; e < NG; ++e) if (raw[e] > g0v) { g0v = raw[e]; e0i = e; }
  int e1i = -1; float g1v = -1.f;
#pragma unroll
  for (int e = 0; e < NG; ++e) if (e != e0i && raw[e] > g1v) { g1v = raw[e]; e1i = e; }

  float denom = g0v + g1v;
  if (denom < 1e-9f) denom = 1e-9f;
  float g0n = g0v / denom, g1n = g1v / denom;

  float p1 = probs[NTOK + token];               // probs[1][b][n], b*NSEQ+n == token
  int rte = (p1 < (g1n / 0.2f)) ? 1 : 0;        // threshold_train = 0.2

  float lse = m + logf(s);

  if (lane < NG) ws->raws[(size_t)token * NG + lane] = raw[lane];
  if (lane == 0) {
    ws->pk[token] = e0i | (e1i << 4) | (rte << 8);
    ws->g0[token] = g0n;  ws->g1[token] = g1n;
    ws->z2[token] = lse * lse;
  }
}

// ---------------- per-(b,e) prefix scans + direct scatter + loss accumulation ----------------
__global__ __launch_bounds__(256) void kscan(const Ws* __restrict__ ws, float* __restrict__ out) {
  __shared__ int   wtot[4];
  __shared__ float wsum[4];
  __shared__ float zsum[4];
  int be = blockIdx.x, b = be >> 3, e = be & 7;
  int t = threadIdx.x, wave = t >> 6, lane = t & 63;
  int base = b * NSEQ;

  // each thread owns 16 consecutive tokens; wave covers contiguous 4KB -> coalesced int4
  int pk[16];
  {
    const int4* pp = (const int4*)(ws->pk + base + t * 16);
#pragma unroll
    for (int j = 0; j < 4; ++j) {
      int4 v = pp[j];
      pk[4*j] = v.x; pk[4*j+1] = v.y; pk[4*j+2] = v.z; pk[4*j+3] = v.w;
    }
  }

  // density_1_proxy partial: sum raw gates for this (b,e)
  float ps = 0.f;
#pragma unroll
  for (int i = 0; i < 16; ++i) ps += ws->raws[(size_t)(base + t * 16 + i) * NG + e];
#pragma unroll
  for (int off = 32; off > 0; off >>= 1) ps += __shfl_xor(ps, off, 64);
  if (lane == 0) wsum[wave] = ps;

  // z-loss slice: this block reduces z2[be*512 .. be*512+512) = 128 float4s
  float zs = 0.f;
  if (t < 128) {
    float4 v = ((const float4*)ws->z2)[be * 128 + t];
    zs = v.x + v.y + v.z + v.w;
  }
#pragma unroll
  for (int off = 32; off > 0; off >>= 1) zs += __shfl_xor(zs, off, 64);
  if (lane == 0) zsum[wave] = zs;

  // ---- k = 0 (always routed) ----
  int cnt = 0;
#pragma unroll
  for (int i = 0; i < 16; ++i) cnt += ((pk[i] & 15) == e);
  int incl = cnt;
#pragma unroll
  for (int off = 1; off < 64; off <<= 1) { int v = __shfl_up(incl, off, 64); if (lane >= off) incl += v; }
  if (lane == 63) wtot[wave] = incl;
  __syncthreads();
  int woff = 0, tot = 0;
#pragma unroll
  for (int w = 0; w < 4; ++w) { int v = wtot[w]; tot += v; if (w < wave) woff += v; }
  int c0 = min(tot, CAPE);
  int p = woff + incl - cnt;          // exclusive prefix for this thread's first token
#pragma unroll
  for (int i = 0; i < 16; ++i) {
    int nn = t * 16 + i;
    if ((pk[i] & 15) == e) {
      if (p < CAPE) {
        size_t o = (size_t)(base + nn) * ROW + e * CAPE + p;
        out[o]        = 1.f;                       // dispatch
        out[DCNT + o] = ws->g0[base + nn];         // combine
      }
      ++p;
    }
  }
  __syncthreads();   // wtot reuse

  // ---- k = 1 (offset by capacity-clipped top-1 count) ----
  cnt = 0;
#pragma unroll
  for (int i = 0; i < 16; ++i) cnt += ((((pk[i] >> 4) & 15) == e) && (pk[i] & 0x100));
  incl = cnt;
#pragma unroll
  for (int off = 1; off < 64; off <<= 1) { int v = __shfl_up(incl, off, 64); if (lane >= off) incl += v; }
  if (lane == 63) wtot[wave] = incl;
  __syncthreads();
  woff = 0;
#pragma unroll
  for (int w = 0; w < 4; ++w) { int v = wtot[w]; if (w < wave) woff += v; }
  p = woff + incl - cnt;
#pragma unroll
  for (int i = 0; i < 16; ++i) {
    int nn = t * 16 + i;
    if ((((pk[i] >> 4) & 15) == e) && (pk[i] & 0x100)) {
      int q = p + c0;
      if (q < CAPE) {
        size_t o = (size_t)(base + nn) * ROW + e * CAPE + q;
        out[o]        = 1.f;                       // dispatch
        out[DCNT + o] = ws->g1[base + nn];         // combine
      }
      ++p;
    }
  }

  if (t == 0) {
    float psum = wsum[0] + wsum[1] + wsum[2] + wsum[3];
    float ztot = zsum[0] + zsum[1] + zsum[2] + zsum[3];
    // balance: sum over 16 (b,e) of (proxy/NSEQ)*(c0/NSEQ), /16 * 64
    atomicAdd(out + 2 * DCNT,     psum * (1.f / NSEQ) * ((float)c0 * (1.f / NSEQ)) * 4.f);
    atomicAdd(out + 2 * DCNT + 1, ztot * (1.f / NTOK));
  }
}

extern "C" void kernel_launch(void* const* d_in, const int* in_sizes, int n_in,
                              void* d_out, int out_size, void* d_ws, size_t ws_size,
                              hipStream_t stream) {
  const float* x     = (const float*)d_in[0];
  const float* W     = (const float*)d_in[1];
  const float* probs = (const float*)d_in[2];
  float* out = (float*)d_out;
  Ws* ws = (Ws*)d_ws;

  kfat<<<5120, 512, 0, stream>>>(x, W, probs, ws, out);
  kscan<<<16, 256, 0, stream>>>(ws, out);
}